// Round 10
// baseline (1091.402 us; speedup 1.0000x reference)
//
#include <hip/hip_runtime.h>

#define NB 4096
#define NT 256

typedef float f32x2 __attribute__((ext_vector_type(2)));

// One 64-thread block = one wave = ONE chain. Lane h owns hidden unit h.
//
// r10 changes vs r9:
//  - intrinsic f32x2 layer2 (r9's asm pk gained nothing: VALU-busy time was
//    flat r7->r9; marshaling movs ate the 32-instr pk savings)
//  - waves_per_eu(4,4): RA budget 128; live set ~120 fits ARCH VGPRs
//    (r8's spill under (4,4) was the asm block's 24-operand peak pressure)
//  - 64-thread blocks: residency granule 1 wave; 16 wg/CU -> 4 waves/SIMD
//    without the 4-wave-block packing constraint (r9 occupancy fell to 28%)
//  - per-step zero-cost pin keeps w2p out of AGPR homing
//
// h1 broadcast via LDS uniform-address b128 reads (conflict-free).
// Layer3 reduction: 3 interleaved DPP butterflies (VALU pipe) + readlane.

template <int ctrl, int rm, int bm>
__device__ __forceinline__ float dpp_add(float v) {
    int m = __builtin_amdgcn_update_dpp(0, __builtin_bit_cast(int, v),
                                        ctrl, rm, bm, true);
    return v + __builtin_bit_cast(float, m);
}

__device__ __forceinline__ float rl63(float v) {
    return __builtin_bit_cast(float,
        __builtin_amdgcn_readlane(__builtin_bit_cast(int, v), 63));
}

__global__ __attribute__((amdgpu_flat_work_group_size(64, 64),
                          amdgpu_waves_per_eu(4, 4)))
void tworeac_kernel(
    const float* __restrict__ u, const float* __restrict__ yseq,
    const float* __restrict__ useq, const float* __restrict__ W1,
    const float* __restrict__ b1, const float* __restrict__ W2,
    const float* __restrict__ b2, const float* __restrict__ W3,
    const float* __restrict__ b3, float* __restrict__ out)
{
    const int lane = threadIdx.x;
    const int b = blockIdx.x;

    __shared__ float h1s[64];

    // ---- weights into registers (lane owns hidden column h = lane) ----
    f32x2 w2p[32];   // {W2[2m][lane], W2[2m+1][lane]} — j-pair form
    #pragma unroll
    for (int m = 0; m < 32; ++m)
        w2p[m] = (f32x2){W2[(2 * m) * 64 + lane], W2[(2 * m + 1) * 64 + lane]};
    float w1x[3], w1y[9], w1u[3], w3r[3];
    #pragma unroll
    for (int i = 0; i < 3; ++i) w1x[i] = W1[i * 64 + lane];
    #pragma unroll
    for (int i = 0; i < 9; ++i) w1y[i] = W1[(3 + i) * 64 + lane];
    #pragma unroll
    for (int i = 0; i < 3; ++i) w1u[i] = W1[(12 + i) * 64 + lane];
    #pragma unroll
    for (int k = 0; k < 3; ++k) w3r[k] = W3[lane * 3 + k];
    const float b1h = b1[lane];
    const float b2h = b2[lane];
    const float b30 = b3[0], b31 = b3[1], b32 = b3[2];

    const float* ub  = u    + (size_t)b * NT;
    const float* ysb = yseq + (size_t)b * NT * 9;
    const float* usb = useq + (size_t)b * NT * 3;
    float*       ob  = out  + (size_t)b * NT * 3;

    float x0 = 0.f, x1 = 0.f, x2 = 0.f;
    float base1 = 0.f, ut = 0.f;

    auto rhs = [&](float xa, float xd, float xc,
                   float& d0, float& d1, float& d2) {
        // layer1 (scalar; only x-part varies per RK stage)
        float h1 = fmaf(xa, w1x[0], fmaf(xd, w1x[1], fmaf(xc, w1x[2], base1)));
        h1 = fmaxf(h1, 0.f);
        h1s[lane] = h1;
        __builtin_amdgcn_wave_barrier();
        // layer2: j-pair f32x2 accumulation; 4 independent accumulators
        f32x2 a0 = (f32x2)0.f, a1 = (f32x2)0.f;
        f32x2 a2 = (f32x2)0.f, a3 = (f32x2)0.f;
        const float4* h4 = reinterpret_cast<const float4*>(&h1s[0]);
        #pragma unroll
        for (int jj = 0; jj < 8; ++jj) {
            float4 qa = h4[2 * jj];
            a0 += (f32x2){qa.x, qa.y} * w2p[4 * jj + 0];
            a1 += (f32x2){qa.z, qa.w} * w2p[4 * jj + 1];
            float4 qb = h4[2 * jj + 1];
            a2 += (f32x2){qb.x, qb.y} * w2p[4 * jj + 2];
            a3 += (f32x2){qb.z, qb.w} * w2p[4 * jj + 3];
        }
        __builtin_amdgcn_wave_barrier();
        f32x2 sp = (a0 + a1) + (a2 + a3);
        float h2 = fmaxf(b2h + (sp.x + sp.y), 0.f);
        // layer3 partials; 3 interleaved DPP butterflies
        float q0 = h2 * w3r[0];
        float q1 = h2 * w3r[1];
        float q2 = h2 * w3r[2];
        #define BLVL(CT, RM, BM)                                        \
            q0 = dpp_add<CT, RM, BM>(q0);                               \
            q1 = dpp_add<CT, RM, BM>(q1);                               \
            q2 = dpp_add<CT, RM, BM>(q2);
        BLVL(0x111, 0xf, 0xf)   // row_shr:1
        BLVL(0x112, 0xf, 0xf)   // row_shr:2
        BLVL(0x114, 0xf, 0xe)   // row_shr:4
        BLVL(0x118, 0xf, 0xc)   // row_shr:8
        BLVL(0x142, 0xa, 0xf)   // row_bcast:15
        BLVL(0x143, 0xc, 0xf)   // row_bcast:31
        #undef BLVL
        float s0 = rl63(q0), s1 = rl63(q1), s2 = rl63(q2);
        // _fg (K1=1, BETA=16, F=0.1, VR=1); fast sqrt/rcp (~1 ulp)
        float s = __builtin_amdgcn_sqrtf(fmaf(16.f, xa, 1.f));
        float r = __builtin_amdgcn_rcpf(1.f + s);
        d0 = fmaf(0.1f, ut - xa, -xa) + (s0 + b30);
        d1 = fmaf(0.5f * xa * (s - 1.f), r, -0.1f * xd) + (s1 + b31);
        d2 = fmaf(2.f * xa, r, -0.1f * xc) + (s2 + b32);
    };

    for (int t = 0; t < NT; ++t) {
        // Zero-cost arch pin once per step: keeps w2p out of AGPR homing
        // (worst case converts per-rhs copies into per-step copies).
        #pragma unroll
        for (int m = 0; m < 32; ++m) asm("" : "+v"(w2p[m]));

        // output = state at entry of step t
        if (lane < 3) {
            float v = (lane == 0) ? x0 : (lane == 1 ? x1 : x2);
            ob[t * 3 + lane] = v;
        }

        ut = ub[t];
        base1 = b1h;
        #pragma unroll
        for (int i = 0; i < 9; ++i) base1 = fmaf(ysb[t * 9 + i], w1y[i], base1);
        #pragma unroll
        for (int i = 0; i < 3; ++i) base1 = fmaf(usb[t * 3 + i], w1u[i], base1);

        float k0, k1v, k2v, a0, a1, a2;
        rhs(x0, x1, x2, k0, k1v, k2v);                       // k1
        a0 = k0; a1 = k1v; a2 = k2v;
        rhs(fmaf(0.005f, k0, x0), fmaf(0.005f, k1v, x1),     // k2
            fmaf(0.005f, k2v, x2), k0, k1v, k2v);
        a0 = fmaf(2.f, k0, a0); a1 = fmaf(2.f, k1v, a1); a2 = fmaf(2.f, k2v, a2);
        rhs(fmaf(0.005f, k0, x0), fmaf(0.005f, k1v, x1),     // k3
            fmaf(0.005f, k2v, x2), k0, k1v, k2v);
        a0 = fmaf(2.f, k0, a0); a1 = fmaf(2.f, k1v, a1); a2 = fmaf(2.f, k2v, a2);
        rhs(fmaf(0.01f, k0, x0), fmaf(0.01f, k1v, x1),       // k4
            fmaf(0.01f, k2v, x2), k0, k1v, k2v);
        a0 += k0; a1 += k1v; a2 += k2v;

        const float c = 0.01f / 6.f;
        x0 = fmaf(c, a0, x0);
        x1 = fmaf(c, a1, x1);
        x2 = fmaf(c, a2, x2);
    }
}

extern "C" void kernel_launch(void* const* d_in, const int* in_sizes, int n_in,
                              void* d_out, int out_size, void* d_ws, size_t ws_size,
                              hipStream_t stream) {
    const float* u    = (const float*)d_in[0];
    const float* yseq = (const float*)d_in[1];
    const float* useq = (const float*)d_in[2];
    const float* W1   = (const float*)d_in[3];
    const float* b1   = (const float*)d_in[4];
    const float* W2   = (const float*)d_in[5];
    const float* b2   = (const float*)d_in[6];
    const float* W3   = (const float*)d_in[7];
    const float* b3   = (const float*)d_in[8];
    float* out = (float*)d_out;

    // 4096 chains, 1 chain per 64-thread block (1 wave/block)
    tworeac_kernel<<<NB, 64, 0, stream>>>(u, yseq, useq, W1, b1, W2, b2,
                                          W3, b3, out);
}